// Round 1
// baseline (154.705 us; speedup 1.0000x reference)
//
#include <hip/hip_runtime.h>
#include <hip/hip_bf16.h>
#include <math.h>

// Problem constants (from reference)
#define NPTS   2097152
#define NDIM   8
#define NBINS  64
// ws layout (floats): [0..65) mesh ; [80..) float4 table[512] = {v1, slope, F_pre, mesh_k} in [d][k] order
#define TBL_OFF 80
#define LOG_BETA (-13.815510557964274f)   // log(1e-6) in fp32

// ---------------- Kernel 1: tiny preprocessing (one block) ----------------
__global__ void cdfq_prep(const float* __restrict__ p, float* __restrict__ ws) {
    __shared__ float mesh[65];
    __shared__ float elmt[64];
    __shared__ float pdf[65][NDIM];
    __shared__ float Fr[64][NDIM];
    const int t = threadIdx.x;

    if (t < 65) {
        float fidx = (float)t - 32.0f;           // idx in [-32, 32]
        float a = fabsf(fidx);
        float x1L = 10.0f * (1.2f - 1.0f) / (powf(1.2f, 32.0f) - 1.0f);
        float xr = (1.0f - powf(1.2f, a)) / (1.0f - 1.2f);
        xr = (fidx >= 0.0f) ? (x1L * xr) : -(x1L * xr);
        xr = (xr + 10.0f) / 20.0f;
        if (t == 0)  xr = 0.0f;
        if (t == 64) xr = 1.0f;
        mesh[t] = xr;
    }
    __syncthreads();
    if (t < 64) elmt[t] = mesh[t + 1] - mesh[t];
    __syncthreads();

    if (t < NDIM) {
        const int d = t;
        // sum of exp(p)*w over 63 interior nodes, w_i = (elmt[i]+elmt[i+1])/2
        float s = 0.0f;
        for (int i = 0; i < 63; ++i)
            s += expf(p[i * NDIM + d]) * (0.5f * (elmt[i] + elmt[i + 1]));
        float scale = (1.0f - (elmt[0] + elmt[63]) * 1e-6f * 0.5f) / s;
        pdf[0][d]  = 1e-6f;
        pdf[64][d] = 1e-6f;
        for (int i = 0; i < 63; ++i) pdf[i + 1][d] = scale * expf(p[i * NDIM + d]);
        // F_ref[k] = sum_{j<k} cell[j], cell[j] = (pdf[j]+pdf[j+1])/2 * elmt[j]
        float acc = 0.0f;
        for (int k = 0; k < 64; ++k) {
            Fr[k][d] = acc;
            acc += 0.5f * (pdf[k][d] + pdf[k + 1][d]) * elmt[k];
        }
    }
    __syncthreads();

    if (t < 65) ws[t] = mesh[t];
    float4* tbl = (float4*)(ws + TBL_OFF);
    for (int idx = t; idx < NDIM * NBINS; idx += blockDim.x) {
        int d = idx >> 6, k = idx & 63;
        float v1 = pdf[k][d];
        float v2 = pdf[k + 1][d];
        tbl[idx] = make_float4(v1, (v2 - v1) / elmt[k], Fr[k][d], mesh[k]);
    }
}

// ---------------- Kernel 2: per-point map (memory-bound) ----------------
__global__ __launch_bounds__(256) void cdfq_main(const float* __restrict__ x,
                                                 const float* __restrict__ logdet_in,
                                                 const float* __restrict__ ws,
                                                 float* __restrict__ y_out,
                                                 float* __restrict__ ld_out,
                                                 int n) {
    __shared__ float  smesh[65];
    __shared__ float4 stbl[NDIM * NBINS];   // [d][k]: lanes in same bin broadcast

    const int t = threadIdx.x;
    for (int i = t; i < 65; i += 256) smesh[i] = ws[i];
    const float4* wt = (const float4*)(ws + TBL_OFF);
    for (int i = t; i < NDIM * NBINS; i += 256) stbl[i] = wt[i];
    __syncthreads();

    const int stride = gridDim.x * blockDim.x;
    for (int i = blockIdx.x * blockDim.x + t; i < n; i += stride) {
        const float4* xv = (const float4*)x + 2 * (size_t)i;
        float4 xa = xv[0];
        float4 xb = xv[1];
        float ld = logdet_in[i];

        float xd[8] = {xa.x, xa.y, xa.z, xa.w, xb.x, xb.y, xb.z, xb.w};
        float yd[8];
        float lsum = 0.0f;

#pragma unroll
        for (int d = 0; d < 8; ++d) {
            float xs = (xd[d] + 10.0f) / 20.0f;
            // branchless binary search: largest k in [0,63] with mesh[k] <= xs
            // (for uncovered xs the result is unused / matches the clip)
            int k = 0;
            if (xs >= smesh[32])     k = 32;
            if (xs >= smesh[k + 16]) k += 16;
            if (xs >= smesh[k + 8])  k += 8;
            if (xs >= smesh[k + 4])  k += 4;
            if (xs >= smesh[k + 2])  k += 2;
            if (xs >= smesh[k + 1])  k += 1;

            float4 tb = stbl[(d << 6) + k];      // {v1, slope, F_pre, mesh[k]}
            float xm  = xs - tb.w;
            bool cov  = (xs >= 0.0f) && (xs < 1.0f);

            float ycov = tb.z + xm * xm * 0.5f * tb.y + xm * tb.x;
            float dld  = cov ? (xm * tb.y + tb.x) : 1.0f;
            float yy   = cov ? ycov : xs;

            lsum += logf(dld);

            yy = yy * 20.0f - 10.0f;
            if (yy > 10.0f)  { yy = 1e-6f * (yy - 10.0f) + 10.0f; lsum += LOG_BETA; }
            if (yy < -10.0f) { yy = 1e-6f * (yy + 10.0f) - 10.0f; lsum += LOG_BETA; }
            yd[d] = yy;
        }

        float4* yo = (float4*)y_out + 2 * (size_t)i;
        yo[0] = make_float4(yd[0], yd[1], yd[2], yd[3]);
        yo[1] = make_float4(yd[4], yd[5], yd[6], yd[7]);
        ld_out[i] = ld + lsum;
    }
}

extern "C" void kernel_launch(void* const* d_in, const int* in_sizes, int n_in,
                              void* d_out, int out_size, void* d_ws, size_t ws_size,
                              hipStream_t stream) {
    const float* x      = (const float*)d_in[0];   // [N, 8]
    const float* logdet = (const float*)d_in[1];   // [N, 1]
    const float* p      = (const float*)d_in[2];   // [63, 8]
    float* ws = (float*)d_ws;

    const int n = in_sizes[1];                     // N points
    float* y_out  = (float*)d_out;                 // [N*8]
    float* ld_out = (float*)d_out + (size_t)n * NDIM;  // [N]

    cdfq_prep<<<1, 256, 0, stream>>>(p, ws);

    const int block = 256;
    const int grid  = 2048;                        // grid-stride, 4 pts/thread
    cdfq_main<<<grid, block, 0, stream>>>(x, logdet, ws, y_out, ld_out, n);
}

// Round 2
// 140.100 us; speedup vs baseline: 1.1042x; 1.1042x over previous
//
#include <hip/hip_runtime.h>
#include <hip/hip_bf16.h>
#include <math.h>

// Problem constants (from reference)
#define NDIM   8
#define NBINS  64
#define LOG_BETA   (-13.815510557964274f)  // log(1e-6)
#define LN2F       0.69314718055994531f
// mesh is geometric: boundary_j (original coords) = x1L*(1.2^j-1)/0.2, j=0..32
// bin index from |x|: g = log2(1 + ALPHA*|x|) / log2(1.2);  ALPHA = (1.2^32-1)/10
#define ALPHA      34.0821892f
#define INV_LOG2R  3.80178401692393f       // 1/log2(1.2)

__global__ __launch_bounds__(256) void cdfq_fused(const float* __restrict__ x,
                                                  const float* __restrict__ logdet_in,
                                                  const float* __restrict__ p,
                                                  float* __restrict__ y_out,
                                                  float* __restrict__ ld_out,
                                                  int n)
{
    __shared__ float  mesh[65];
    __shared__ float  elmt[64];
    __shared__ float  sc[NDIM];
    __shared__ float  pdfs[NDIM][65];      // [d][k] — bank-friendly (65 stride)
    __shared__ float  cell[NDIM][64];
    __shared__ float4 stbl[NDIM * NBINS];  // [d][k]: {v1, slope, F_pre, mesh_k}

    const int t = threadIdx.x;

    // ---- prep phase (redundant per block; ~1 µs, removes a serializing launch) ----
    if (t < 65) {
        float fidx = (float)t - 32.0f;
        float a = fabsf(fidx);
        float x1L = 2.0f / (powf(1.2f, 32.0f) - 1.0f);
        float xr = x1L * (powf(1.2f, a) - 1.0f) / 0.2f;
        xr = (fidx >= 0.0f) ? xr : -xr;
        xr = (xr + 10.0f) / 20.0f;
        if (t == 0)  xr = 0.0f;
        if (t == 64) xr = 1.0f;
        mesh[t] = xr;
    }
    for (int idx = t; idx < 63 * NDIM; idx += 256) {      // exp(p) -> pdfs[d][k+1]
        int d = idx & 7, k = idx >> 3;
        pdfs[d][k + 1] = expf(p[k * NDIM + d]);
    }
    if (t < NDIM) { pdfs[t][0] = 1e-6f; pdfs[t][64] = 1e-6f; }
    __syncthreads();
    if (t < 64) elmt[t] = mesh[t + 1] - mesh[t];
    __syncthreads();

    if (t < 64) {   // wave 0: per-dim normalization scale via shuffle reduce
        for (int d = 0; d < NDIM; ++d) {
            float w = 0.0f;
            if (t < 63) w = pdfs[d][t + 1] * 0.5f * (elmt[t] + elmt[t + 1]);
            for (int off = 32; off > 0; off >>= 1) w += __shfl_down(w, off);
            if (t == 0) sc[d] = (1.0f - (elmt[0] + elmt[63]) * 5e-7f) / w;
        }
    }
    __syncthreads();
    for (int idx = t; idx < 63 * NDIM; idx += 256) {      // apply scale
        int d = idx & 7, k = idx >> 3;
        pdfs[d][k + 1] *= sc[d];
    }
    __syncthreads();
    for (int idx = t; idx < NDIM * NBINS; idx += 256) {   // cell integrals
        int d = idx >> 6, k = idx & 63;
        cell[d][k] = 0.5f * (pdfs[d][k] + pdfs[d][k + 1]) * elmt[k];
    }
    __syncthreads();
    if (t < 64) {   // wave 0: exclusive scan per dim + pack table
        for (int d = 0; d < NDIM; ++d) {
            float c0 = cell[d][t];
            float v = c0;
            for (int off = 1; off < 64; off <<= 1) {
                float w = __shfl_up(v, off);
                if (t >= off) v += w;
            }
            float Fpre = v - c0;                 // exclusive prefix
            float v1 = pdfs[d][t];
            float v2 = pdfs[d][t + 1];
            stbl[d * 64 + t] = make_float4(v1, (v2 - v1) / elmt[t], Fpre, mesh[t]);
        }
    }
    __syncthreads();

    // ---- main phase: memory-bound point map ----
    const int stride = gridDim.x * blockDim.x;
    for (int i = blockIdx.x * blockDim.x + t; i < n; i += stride) {
        const float4* xv = (const float4*)x + 2 * (size_t)i;
        float4 xa = xv[0];
        float4 xb = xv[1];
        float ld = logdet_in[i];

        float xd[8] = {xa.x, xa.y, xa.z, xa.w, xb.x, xb.y, xb.z, xb.w};
        float yd[8], dd[8];

#pragma unroll
        for (int d = 0; d < 8; ++d) {
            float xo = xd[d];
            float xs = fmaf(xo, 0.05f, 0.5f);            // (x+10)/20 to 1 ulp
            float u  = fabsf(xo);
            // analytic bin: g = log2(1 + alpha*u)/log2(1.2); one v_log_f32
            float g  = __log2f(fmaf(ALPHA, u, 1.0f)) * INV_LOG2R;
            int jp = (int)fminf(g, 31.0f);               // floor, x >= 0 side
            int jn = (int)ceilf(fminf(g, 32.0f));        // ceil,  x <  0 side
            int k  = (xo >= 0.0f) ? (32 + jp) : (32 - jn);

            float4 tb = stbl[(d << 6) + k];              // {v1, slope, F_pre, mesh_k}
            float xm  = xs - tb.w;
            bool cov  = (xs >= 0.0f) && (xs < 1.0f);

            float yc = tb.z + xm * fmaf(0.5f * xm, tb.y, tb.x);
            float dl = fmaf(xm, tb.y, tb.x);
            float yy = cov ? yc : xs;
            dd[d]    = cov ? dl : 1.0f;

            yy = fmaf(yy, 20.0f, -10.0f);
            if (yy > 10.0f)  { yy = fmaf(1e-6f, yy - 10.0f, 10.0f);  ld += LOG_BETA; }
            if (yy < -10.0f) { yy = fmaf(1e-6f, yy + 10.0f, -10.0f); ld += LOG_BETA; }
            yd[d] = yy;
        }

        // sum of logs as logs of pairwise products: 4 x v_log_f32
        // (pair product >= (1e-6)^2 = 1e-12 — no fp32 underflow)
        float l01 = __log2f(dd[0] * dd[1]);
        float l23 = __log2f(dd[2] * dd[3]);
        float l45 = __log2f(dd[4] * dd[5]);
        float l67 = __log2f(dd[6] * dd[7]);
        ld = fmaf((l01 + l23) + (l45 + l67), LN2F, ld);

        float4* yo = (float4*)y_out + 2 * (size_t)i;
        yo[0] = make_float4(yd[0], yd[1], yd[2], yd[3]);
        yo[1] = make_float4(yd[4], yd[5], yd[6], yd[7]);
        ld_out[i] = ld;
    }
}

extern "C" void kernel_launch(void* const* d_in, const int* in_sizes, int n_in,
                              void* d_out, int out_size, void* d_ws, size_t ws_size,
                              hipStream_t stream) {
    const float* x      = (const float*)d_in[0];   // [N, 8]
    const float* logdet = (const float*)d_in[1];   // [N, 1]
    const float* p      = (const float*)d_in[2];   // [63, 8]

    const int n = in_sizes[1];                     // N points
    float* y_out  = (float*)d_out;                 // [N*8]
    float* ld_out = (float*)d_out + (size_t)n * NDIM;  // [N]

    const int block = 256;
    const int grid  = 2048;                        // grid-stride, 4 pts/thread
    cdfq_fused<<<grid, block, 0, stream>>>(x, logdet, p, y_out, ld_out, n);
}